// Round 3
// baseline (804.952 us; speedup 1.0000x reference)
//
#include <hip/hip_runtime.h>
#include <hip/hip_bf16.h>
#include <cstdint>
#include <cmath>

// ---------------------------------------------------------------------------
// Swin3D block: LN1 -> shift+window -> QKV -> win-attn(+relbias+mask) -> proj
//               -> unshift+residual -> LN2 -> FC1+GELU -> FC2 -> +residual
// v2: GEMM = 128x128 tile, BK=64, double-buffered LDS with prefetch overlap
//     (T3-minimum), XOR-swizzled LDS via pre-swizzled global source (T2),
//     XCD-chunked block swizzle (T1). Attn 4 waves/block. LN float2 loads.
// ---------------------------------------------------------------------------

typedef __attribute__((ext_vector_type(4))) float f32x4;
typedef __attribute__((ext_vector_type(8))) __bf16 bf16x8_t;

static __device__ __forceinline__ short f2bf(float f) {
  unsigned u = __builtin_bit_cast(unsigned, f);
  unsigned lsb = (u >> 16) & 1u;
  u += 0x7fffu + lsb;
  return (short)(u >> 16);
}

static __device__ __forceinline__ void gload_lds16(const short* g, short* l) {
  __builtin_amdgcn_global_load_lds(
      (const __attribute__((address_space(1))) void*)g,
      (__attribute__((address_space(3))) void*)l, 16, 0, 0);
}

// ---------------- workspace layout (bytes), total ~255.2 MB ----------------
static constexpr size_t OFF_Q    = 0;
static constexpr size_t OFF_K    = 50331648;
static constexpr size_t OFF_V    = 100663296;                // qkv end 150994944
static constexpr size_t OFF_HID  = 0;                        // over dead q/k/v
static constexpr size_t OFF_WIN  = 201326592;                // win / owin / h2 share
static constexpr size_t OFF_WQ   = OFF_WIN + 50331648;       // wqkv^T [1152][384]
static constexpr size_t OFF_WP   = OFF_WQ  + 884736;         // wproj^T [384][384]
static constexpr size_t OFF_W1   = OFF_WP  + 294912;         // wfc1^T [1536][384]
static constexpr size_t OFF_W2   = OFF_W1  + 1179648;        // wfc2^T [384][1536]

// ---------------- weight fp32 -> bf16 transpose ----------------
__global__ void k_w2bf_t(const float* __restrict__ w, short* __restrict__ wt,
                         int K, int N) {
  int idx = blockIdx.x * 256 + threadIdx.x;
  if (idx >= K * N) return;
  int k = idx / N, n = idx - k * N;
  wt[(size_t)n * K + k] = f2bf(w[idx]);
}

// ---------------- LN1 + roll(-2,-2,-2) + window partition -> bf16 ----------
__global__ __launch_bounds__(256) void k_ln1_window(
    const float* __restrict__ x, const float* __restrict__ gw,
    const float* __restrict__ gb, short* __restrict__ win) {
  int slot = blockIdx.x * 4 + (threadIdx.x >> 6);   // widx*64 + n, 0..65535
  int lane = threadIdx.x & 63;
  int widx = slot >> 6, n = slot & 63;
  int bidx = widx >> 8, wloc = widx & 255;
  int z = ((wloc >> 6) << 2) + (n >> 4);
  int h = (((wloc >> 3) & 7) << 2) + ((n >> 2) & 3);
  int w = ((wloc & 7) << 2) + (n & 3);
  int zs = (z + 2) & 15, hs = (h + 2) & 31, ws = (w + 2) & 31;
  const float* xp = x + ((size_t)bidx * 16384 + zs * 1024 + hs * 32 + ws) * 384;
  float2 u[3]; float s = 0.f, s2 = 0.f;
#pragma unroll
  for (int j = 0; j < 3; j++) {
    u[j] = *(const float2*)(xp + lane * 2 + j * 128);
    s += u[j].x + u[j].y; s2 += u[j].x * u[j].x + u[j].y * u[j].y;
  }
#pragma unroll
  for (int o = 1; o < 64; o <<= 1) { s += __shfl_xor(s, o); s2 += __shfl_xor(s2, o); }
  float mu = s * (1.f / 384.f);
  float rinv = rsqrtf(s2 * (1.f / 384.f) - mu * mu + 1e-5f);
  short* wp = win + (size_t)slot * 384;
#pragma unroll
  for (int j = 0; j < 3; j++) {
    int c = lane * 2 + j * 128;
    ushort2 o;
    o.x = (unsigned short)f2bf((u[j].x - mu) * rinv * gw[c] + gb[c]);
    o.y = (unsigned short)f2bf((u[j].y - mu) * rinv * gw[c + 1] + gb[c + 1]);
    *(ushort2*)(wp + c) = o;
  }
}

// ---------------- LN2 (plain, token order) -> bf16 ----------------
__global__ __launch_bounds__(256) void k_ln2(
    const float* __restrict__ x2, const float* __restrict__ gw,
    const float* __restrict__ gb, short* __restrict__ h2) {
  int t = blockIdx.x * 4 + (threadIdx.x >> 6);
  int lane = threadIdx.x & 63;
  const float* xp = x2 + (size_t)t * 384;
  float2 u[3]; float s = 0.f, s2 = 0.f;
#pragma unroll
  for (int j = 0; j < 3; j++) {
    u[j] = *(const float2*)(xp + lane * 2 + j * 128);
    s += u[j].x + u[j].y; s2 += u[j].x * u[j].x + u[j].y * u[j].y;
  }
#pragma unroll
  for (int o = 1; o < 64; o <<= 1) { s += __shfl_xor(s, o); s2 += __shfl_xor(s2, o); }
  float mu = s * (1.f / 384.f);
  float rinv = rsqrtf(s2 * (1.f / 384.f) - mu * mu + 1e-5f);
  short* hp = h2 + (size_t)t * 384;
#pragma unroll
  for (int j = 0; j < 3; j++) {
    int c = lane * 2 + j * 128;
    ushort2 o;
    o.x = (unsigned short)f2bf((u[j].x - mu) * rinv * gw[c] + gb[c]);
    o.y = (unsigned short)f2bf((u[j].y - mu) * rinv * gw[c + 1] + gb[c + 1]);
    *(ushort2*)(hp + c) = o;
  }
}

// ---------------- tiled bf16 MFMA GEMM: C = A[M][K] @ Bt[N][K]^T ------------
// 128x128 tile, BK=64, 256 thr (4 waves), double-buffered LDS + prefetch.
// LDS rows are XOR-swizzled (16B granule, key=(row&7)) via pre-swizzled
// global source; reads apply the same XOR -> conflict-free ds_read_b128.
// EPI: 0=QKV scatter (q scaled, v transposed), 1=proj+unshift+residual->f32,
//      2=FC1+GELU->bf16, 3=FC2+residual->f32 out (in-place aux==of32 ok)
template <int EPI, int KDIM>
__global__ __launch_bounds__(256) void k_gemm(
    const short* __restrict__ A, const short* __restrict__ Bt,
    const float* __restrict__ bias, short* __restrict__ ob0,
    short* __restrict__ ob1, short* __restrict__ ob2,
    const float* __restrict__ aux, float* __restrict__ of32) {
  __shared__ short As[16384];   // 2 bufs x [128][64]
  __shared__ short Bs[16384];
  const int tid = threadIdx.x;
  const int wave = tid >> 6, lane = tid & 63;
  const int g = lane >> 4, li = lane & 15;

  // T1: bijective XCD-chunked swizzle (nwg % 8 == 0 for all our launches)
  const int nx = gridDim.x;
  const int nwg = nx * gridDim.y;
  int bid = blockIdx.y * nx + blockIdx.x;
  const int cpx = nwg >> 3;
  bid = (bid & 7) * cpx + (bid >> 3);
  const int m0 = (bid / nx) << 7, n0 = (bid % nx) << 7;

  // staging: thread t covers row (t>>3) (+32 per pass), 16B col (t&7),
  // source col8 pre-swizzled so LDS stays linear while holding swizzled data
  const int srow = tid >> 3;
  const int sc8 = (tid & 7) ^ (srow & 7);
  const short* gA = A + (size_t)(m0 + srow) * KDIM + sc8 * 8;
  const short* gB = Bt + (size_t)(n0 + srow) * KDIM + sc8 * 8;
  short* lA = As + wave * 512;   // wave-uniform dest base (+p*2048, +buf*8192)
  short* lB = Bs + wave * 512;

  const int wm = wave >> 1, wn = wave & 1;
  const int kx = (li & 7) << 3;          // short-index XOR key for reads
  const short* ra = As + (wm * 64 + li) * 64;
  const short* rb = Bs + (wn * 64 + li) * 64;
  const int c00 = (g * 8) ^ kx;          // k-slice 0 col offset (shorts)
  const int c32 = (32 + g * 8) ^ kx;     // k-slice 1

  f32x4 acc[4][4] = {};

#define STAGE(buf, kt)                                                        \
  do {                                                                        \
    _Pragma("unroll") for (int p = 0; p < 4; p++) {                           \
      gload_lds16(gA + (size_t)(p * 32) * KDIM + (kt),                        \
                  lA + (buf) * 8192 + p * 2048);                              \
      gload_lds16(gB + (size_t)(p * 32) * KDIM + (kt),                        \
                  lB + (buf) * 8192 + p * 2048);                              \
    }                                                                         \
  } while (0)

#define COMPUTE(buf)                                                          \
  do {                                                                        \
    const short* ra_ = ra + (buf) * 8192;                                     \
    const short* rb_ = rb + (buf) * 8192;                                     \
    bf16x8_t a0[4], a1[4], b0[4], b1[4];                                      \
    _Pragma("unroll") for (int i = 0; i < 4; i++) {                           \
      a0[i] = *(const bf16x8_t*)(ra_ + i * 1024 + c00);                       \
      a1[i] = *(const bf16x8_t*)(ra_ + i * 1024 + c32);                       \
      b0[i] = *(const bf16x8_t*)(rb_ + i * 1024 + c00);                       \
      b1[i] = *(const bf16x8_t*)(rb_ + i * 1024 + c32);                       \
    }                                                                         \
    _Pragma("unroll") for (int mi = 0; mi < 4; mi++)                          \
        _Pragma("unroll") for (int ni = 0; ni < 4; ni++) acc[mi][ni] =        \
        __builtin_amdgcn_mfma_f32_16x16x32_bf16(a0[mi], b0[ni], acc[mi][ni],  \
                                                0, 0, 0);                     \
    _Pragma("unroll") for (int mi = 0; mi < 4; mi++)                          \
        _Pragma("unroll") for (int ni = 0; ni < 4; ni++) acc[mi][ni] =        \
        __builtin_amdgcn_mfma_f32_16x16x32_bf16(a1[mi], b1[ni], acc[mi][ni],  \
                                                0, 0, 0);                     \
  } while (0)

  constexpr int NT = KDIM / 64;
  STAGE(0, 0);
  asm volatile("s_waitcnt vmcnt(0)" ::: "memory");
  __syncthreads();
  int cur = 0;
  for (int t = 0; t < NT - 1; ++t) {
    STAGE(cur ^ 1, (t + 1) * 64);   // prefetch next tile (stays in flight)
    COMPUTE(cur);                   // ds_read + MFMA overlap the loads
    asm volatile("s_waitcnt vmcnt(0)" ::: "memory");
    __syncthreads();
    cur ^= 1;
  }
  COMPUTE(cur);
#undef STAGE
#undef COMPUTE

  // epilogue: row = m0+wm*64+mi*16+g*4+r ; col = n0+wn*64+ni*16+li
#pragma unroll
  for (int mi = 0; mi < 4; mi++) {
#pragma unroll
    for (int ni = 0; ni < 4; ni++) {
      const int col = n0 + wn * 64 + ni * 16 + li;
      const float bc = bias[col];
      const int rbase = m0 + wm * 64 + mi * 16 + g * 4;
      if constexpr (EPI == 0) {
        const int s = col / 384;
        const int rem = col - s * 384;
        const int head = rem >> 5, d = rem & 31;
#pragma unroll
        for (int r = 0; r < 4; r++) {
          const int row = rbase + r;
          const int widx = row >> 6, n = row & 63;
          float v = acc[mi][ni][r] + bc;
          if (s == 0)
            ob0[(((size_t)widx * 12 + head) * 64 + n) * 32 + d] =
                f2bf(v * 0.17677669529663687f);  // fold q scale (32^-1/2)
          else if (s == 1)
            ob1[(((size_t)widx * 12 + head) * 64 + n) * 32 + d] = f2bf(v);
          else  // v stored transposed: [widx][head][d][n]
            ob2[(((size_t)widx * 12 + head) * 32 + d) * 64 + n] = f2bf(v);
        }
      } else if constexpr (EPI == 1) {
#pragma unroll
        for (int r = 0; r < 4; r++) {
          const int row = rbase + r;
          const int widx = row >> 6, n = row & 63;
          const int wloc = widx & 255, bb = widx >> 8;
          const int z = ((wloc >> 6) << 2) + (n >> 4);
          const int h = (((wloc >> 3) & 7) << 2) + ((n >> 2) & 3);
          const int w = ((wloc & 7) << 2) + (n & 3);
          const int zs = (z + 2) & 15, hs = (h + 2) & 31, wsx = (w + 2) & 31;
          const size_t t = (size_t)bb * 16384 + zs * 1024 + hs * 32 + wsx;
          of32[t * 384 + col] = aux[t * 384 + col] + acc[mi][ni][r] + bc;
        }
      } else if constexpr (EPI == 2) {
#pragma unroll
        for (int r = 0; r < 4; r++) {
          const int row = rbase + r;
          float v = acc[mi][ni][r] + bc;
          ob0[(size_t)row * 1536 + col] =
              f2bf(0.5f * v * (1.f + erff(v * 0.70710678118654752f)));
        }
      } else {
#pragma unroll
        for (int r = 0; r < 4; r++) {
          const int row = rbase + r;
          of32[(size_t)row * 384 + col] =
              aux[(size_t)row * 384 + col] + acc[mi][ni][r] + bc;
        }
      }
    }
  }
}

// ---------------- windowed attention: 4 waves/block, 1 wave per (win,head) --
__global__ __launch_bounds__(256) void k_attn(
    const short* __restrict__ qb, const short* __restrict__ kb,
    const short* __restrict__ vb, const float* __restrict__ relb,
    short* __restrict__ owin) {
  __shared__ short pt[4][5120];  // per-wave [qn][kn], stride 80
  const int wave = threadIdx.x >> 6;
  const int wh_ = blockIdx.x * 4 + wave;   // widx*12 + head
  const int widx = wh_ / 12, head = wh_ - widx * 12;
  const int lane = threadIdx.x & 63;
  const int g = lane >> 4, li = lane & 15;
  const short* qp = qb + (size_t)wh_ * 2048;
  const short* kp = kb + (size_t)wh_ * 2048;
  const short* vp = vb + (size_t)wh_ * 2048;  // [d][n] layout
  short* ptw = pt[wave];
  bf16x8_t kf[4], qf[4];
#pragma unroll
  for (int t = 0; t < 4; t++) {
    kf[t] = *(const bf16x8_t*)(kp + (t * 16 + li) * 32 + g * 8);
    qf[t] = *(const bf16x8_t*)(qp + (t * 16 + li) * 32 + g * 8);
  }
  f32x4 zero = {0.f, 0.f, 0.f, 0.f};
  f32x4 st[4][4];  // [ti: kn-block][tj: qn-block]
#pragma unroll
  for (int ti = 0; ti < 4; ti++)
#pragma unroll
    for (int tj = 0; tj < 4; tj++)
      st[ti][tj] = __builtin_amdgcn_mfma_f32_16x16x32_bf16(kf[ti], qf[tj], zero, 0, 0, 0);
  const int wloc = widx & 255;
  const int wz = wloc >> 6, wh2 = (wloc >> 3) & 7, ww2 = wloc & 7;
#pragma unroll
  for (int tj = 0; tj < 4; tj++) {
    const int qn = tj * 16 + li;
    const int qz = qn >> 4, qh = (qn >> 2) & 3, qw = qn & 3;
    const int cq = ((wz < 3) ? 0 : ((qz < 2) ? 1 : 2)) * 9 +
                   ((wh2 < 7) ? 0 : ((qh < 2) ? 1 : 2)) * 3 +
                   ((ww2 < 7) ? 0 : ((qw < 2) ? 1 : 2));
    float mx = -1e30f;
#pragma unroll
    for (int ti = 0; ti < 4; ti++) {
#pragma unroll
      for (int r = 0; r < 4; r++) {
        const int kn = ti * 16 + g * 4 + r;
        const int kz = kn >> 4, kh = (kn >> 2) & 3, kw = kn & 3;
        const int ck = ((wz < 3) ? 0 : ((kz < 2) ? 1 : 2)) * 9 +
                       ((wh2 < 7) ? 0 : ((kh < 2) ? 1 : 2)) * 3 +
                       ((ww2 < 7) ? 0 : ((kw < 2) ? 1 : 2));
        const int idx = (qz - kz + 3) * 49 + (qh - kh + 3) * 7 + (qw - kw + 3);
        float v = st[ti][tj][r] + relb[idx * 12 + head] + ((ck == cq) ? 0.f : -100.f);
        st[ti][tj][r] = v;
        mx = fmaxf(mx, v);
      }
    }
    mx = fmaxf(mx, __shfl_xor(mx, 16));
    mx = fmaxf(mx, __shfl_xor(mx, 32));
    float sum = 0.f;
#pragma unroll
    for (int ti = 0; ti < 4; ti++)
#pragma unroll
      for (int r = 0; r < 4; r++) {
        float e = __expf(st[ti][tj][r] - mx);
        st[ti][tj][r] = e;
        sum += e;
      }
    sum += __shfl_xor(sum, 16);
    sum += __shfl_xor(sum, 32);
    const float rs = 1.f / sum;
#pragma unroll
    for (int ti = 0; ti < 4; ti++)
#pragma unroll
      for (int r = 0; r < 4; r++)
        ptw[qn * 80 + ti * 16 + g * 4 + r] = f2bf(st[ti][tj][r] * rs);
  }
  __syncthreads();
  f32x4 o[4][2] = {};
#pragma unroll
  for (int kb2 = 0; kb2 < 2; kb2++) {
    bf16x8_t pa[4], bv[2];
#pragma unroll
    for (int tq = 0; tq < 4; tq++)
      pa[tq] = *(const bf16x8_t*)(ptw + (tq * 16 + li) * 80 + kb2 * 32 + g * 8);
#pragma unroll
    for (int td = 0; td < 2; td++)
      bv[td] = *(const bf16x8_t*)(vp + (td * 16 + li) * 64 + kb2 * 32 + g * 8);
#pragma unroll
    for (int tq = 0; tq < 4; tq++)
#pragma unroll
      for (int td = 0; td < 2; td++)
        o[tq][td] = __builtin_amdgcn_mfma_f32_16x16x32_bf16(pa[tq], bv[td], o[tq][td], 0, 0, 0);
  }
#pragma unroll
  for (int tq = 0; tq < 4; tq++)
#pragma unroll
    for (int td = 0; td < 2; td++)
#pragma unroll
      for (int r = 0; r < 4; r++) {
        const int qn = tq * 16 + g * 4 + r;
        const int d = td * 16 + li;
        owin[((size_t)widx * 64 + qn) * 384 + head * 32 + d] = f2bf(o[tq][td][r]);
      }
}

// ---------------------------------------------------------------------------
extern "C" void kernel_launch(void* const* d_in, const int* in_sizes, int n_in,
                              void* d_out, int out_size, void* d_ws,
                              size_t ws_size, hipStream_t stream) {
  (void)in_sizes; (void)n_in; (void)out_size; (void)ws_size;
  const float* x      = (const float*)d_in[0];
  const float* n1g    = (const float*)d_in[1];
  const float* n1b    = (const float*)d_in[2];
  const float* qkv_w  = (const float*)d_in[3];
  const float* qkv_b  = (const float*)d_in[4];
  const float* proj_w = (const float*)d_in[5];
  const float* proj_b = (const float*)d_in[6];
  const float* relb   = (const float*)d_in[7];
  const float* n2g    = (const float*)d_in[8];
  const float* n2b    = (const float*)d_in[9];
  const float* fc1_w  = (const float*)d_in[10];
  const float* fc1_b  = (const float*)d_in[11];
  const float* fc2_w  = (const float*)d_in[12];
  const float* fc2_b  = (const float*)d_in[13];
  float* out = (float*)d_out;
  char* ws = (char*)d_ws;

  short* qbuf = (short*)(ws + OFF_Q);
  short* kbuf = (short*)(ws + OFF_K);
  short* vbuf = (short*)(ws + OFF_V);
  short* hid  = (short*)(ws + OFF_HID);
  short* win  = (short*)(ws + OFF_WIN);   // shared: win -> owin -> h2
  short* owin = (short*)(ws + OFF_WIN);
  short* h2   = (short*)(ws + OFF_WIN);
  float* x2   = out;                      // fp32 residual lives in d_out
  short* wq   = (short*)(ws + OFF_WQ);
  short* wp   = (short*)(ws + OFF_WP);
  short* w1   = (short*)(ws + OFF_W1);
  short* w2   = (short*)(ws + OFF_W2);

  // weights -> bf16 transposed [N][K]
  k_w2bf_t<<<(384 * 1152 + 255) / 256, 256, 0, stream>>>(qkv_w, wq, 384, 1152);
  k_w2bf_t<<<(384 * 384 + 255) / 256, 256, 0, stream>>>(proj_w, wp, 384, 384);
  k_w2bf_t<<<(384 * 1536 + 255) / 256, 256, 0, stream>>>(fc1_w, w1, 384, 1536);
  k_w2bf_t<<<(1536 * 384 + 255) / 256, 256, 0, stream>>>(fc2_w, w2, 1536, 384);

  // LN1 + shift + window partition
  k_ln1_window<<<16384, 256, 0, stream>>>(x, n1g, n1b, win);
  // QKV GEMM [65536,384]@[384,1152]
  k_gemm<0, 384><<<dim3(9, 512), 256, 0, stream>>>(win, wq, qkv_b, qbuf, kbuf,
                                                   vbuf, nullptr, nullptr);
  // windowed attention (4 window-heads per block)
  k_attn<<<3072, 256, 0, stream>>>(qbuf, kbuf, vbuf, relb, owin);
  // proj GEMM + unshift + residual -> x2 (in d_out)
  k_gemm<1, 384><<<dim3(3, 512), 256, 0, stream>>>(owin, wp, proj_b, nullptr,
                                                   nullptr, nullptr, x, x2);
  // LN2
  k_ln2<<<16384, 256, 0, stream>>>(x2, n2g, n2b, h2);
  // FC1 + GELU
  k_gemm<2, 384><<<dim3(12, 512), 256, 0, stream>>>(h2, w1, fc1_b, hid, nullptr,
                                                    nullptr, nullptr, nullptr);
  // FC2 + residual -> out (in-place: aux == of32 == d_out)
  k_gemm<3, 1536><<<dim3(3, 512), 256, 0, stream>>>(hid, w2, fc2_b, nullptr,
                                                    nullptr, nullptr, x2, out);
}

// Round 4
// 798.988 us; speedup vs baseline: 1.0075x; 1.0075x over previous
//
#include <hip/hip_runtime.h>
#include <hip/hip_bf16.h>
#include <cstdint>
#include <cmath>

// ---------------------------------------------------------------------------
// Swin3D block: LN1 -> shift+window -> QKV -> win-attn(+relbias+mask) -> proj
//               -> unshift+residual -> LN2 -> FC1+GELU -> FC2 -> +residual
// v3 GEMM: BM=256 x BN=128, 4 waves each 128x64, BK=32, TRIPLE-buffered LDS
//          with counted vmcnt(12) (T4 - never drain in loop), raw s_barrier,
//          row-pair XOR swizzle (conflict-free), T1 XCD-chunked swizzle.
// ---------------------------------------------------------------------------

typedef __attribute__((ext_vector_type(4))) float f32x4;
typedef __attribute__((ext_vector_type(8))) __bf16 bf16x8_t;

static __device__ __forceinline__ short f2bf(float f) {
  unsigned u = __builtin_bit_cast(unsigned, f);
  unsigned lsb = (u >> 16) & 1u;
  u += 0x7fffu + lsb;
  return (short)(u >> 16);
}

static __device__ __forceinline__ void gload_lds16(const short* g, short* l) {
  __builtin_amdgcn_global_load_lds(
      (const __attribute__((address_space(1))) void*)g,
      (__attribute__((address_space(3))) void*)l, 16, 0, 0);
}

// ---------------- workspace layout (bytes), total ~255.2 MB ----------------
static constexpr size_t OFF_Q    = 0;
static constexpr size_t OFF_K    = 50331648;
static constexpr size_t OFF_V    = 100663296;                // qkv end 150994944
static constexpr size_t OFF_HID  = 0;                        // over dead q/k/v
static constexpr size_t OFF_WIN  = 201326592;                // win / owin / h2 share
static constexpr size_t OFF_WQ   = OFF_WIN + 50331648;       // wqkv^T [1152][384]
static constexpr size_t OFF_WP   = OFF_WQ  + 884736;         // wproj^T [384][384]
static constexpr size_t OFF_W1   = OFF_WP  + 294912;         // wfc1^T [1536][384]
static constexpr size_t OFF_W2   = OFF_W1  + 1179648;        // wfc2^T [384][1536]

// ---------------- weight fp32 -> bf16 transpose ----------------
__global__ void k_w2bf_t(const float* __restrict__ w, short* __restrict__ wt,
                         int K, int N) {
  int idx = blockIdx.x * 256 + threadIdx.x;
  if (idx >= K * N) return;
  int k = idx / N, n = idx - k * N;
  wt[(size_t)n * K + k] = f2bf(w[idx]);
}

// ---------------- LN1 + roll(-2,-2,-2) + window partition -> bf16 ----------
__global__ __launch_bounds__(256) void k_ln1_window(
    const float* __restrict__ x, const float* __restrict__ gw,
    const float* __restrict__ gb, short* __restrict__ win) {
  int slot = blockIdx.x * 4 + (threadIdx.x >> 6);   // widx*64 + n, 0..65535
  int lane = threadIdx.x & 63;
  int widx = slot >> 6, n = slot & 63;
  int bidx = widx >> 8, wloc = widx & 255;
  int z = ((wloc >> 6) << 2) + (n >> 4);
  int h = (((wloc >> 3) & 7) << 2) + ((n >> 2) & 3);
  int w = ((wloc & 7) << 2) + (n & 3);
  int zs = (z + 2) & 15, hs = (h + 2) & 31, ws = (w + 2) & 31;
  const float* xp = x + ((size_t)bidx * 16384 + zs * 1024 + hs * 32 + ws) * 384;
  float2 u[3]; float s = 0.f, s2 = 0.f;
#pragma unroll
  for (int j = 0; j < 3; j++) {
    u[j] = *(const float2*)(xp + lane * 2 + j * 128);
    s += u[j].x + u[j].y; s2 += u[j].x * u[j].x + u[j].y * u[j].y;
  }
#pragma unroll
  for (int o = 1; o < 64; o <<= 1) { s += __shfl_xor(s, o); s2 += __shfl_xor(s2, o); }
  float mu = s * (1.f / 384.f);
  float rinv = rsqrtf(s2 * (1.f / 384.f) - mu * mu + 1e-5f);
  short* wp = win + (size_t)slot * 384;
#pragma unroll
  for (int j = 0; j < 3; j++) {
    int c = lane * 2 + j * 128;
    ushort2 o;
    o.x = (unsigned short)f2bf((u[j].x - mu) * rinv * gw[c] + gb[c]);
    o.y = (unsigned short)f2bf((u[j].y - mu) * rinv * gw[c + 1] + gb[c + 1]);
    *(ushort2*)(wp + c) = o;
  }
}

// ---------------- LN2 (plain, token order) -> bf16 ----------------
__global__ __launch_bounds__(256) void k_ln2(
    const float* __restrict__ x2, const float* __restrict__ gw,
    const float* __restrict__ gb, short* __restrict__ h2) {
  int t = blockIdx.x * 4 + (threadIdx.x >> 6);
  int lane = threadIdx.x & 63;
  const float* xp = x2 + (size_t)t * 384;
  float2 u[3]; float s = 0.f, s2 = 0.f;
#pragma unroll
  for (int j = 0; j < 3; j++) {
    u[j] = *(const float2*)(xp + lane * 2 + j * 128);
    s += u[j].x + u[j].y; s2 += u[j].x * u[j].x + u[j].y * u[j].y;
  }
#pragma unroll
  for (int o = 1; o < 64; o <<= 1) { s += __shfl_xor(s, o); s2 += __shfl_xor(s2, o); }
  float mu = s * (1.f / 384.f);
  float rinv = rsqrtf(s2 * (1.f / 384.f) - mu * mu + 1e-5f);
  short* hp = h2 + (size_t)t * 384;
#pragma unroll
  for (int j = 0; j < 3; j++) {
    int c = lane * 2 + j * 128;
    ushort2 o;
    o.x = (unsigned short)f2bf((u[j].x - mu) * rinv * gw[c] + gb[c]);
    o.y = (unsigned short)f2bf((u[j].y - mu) * rinv * gw[c + 1] + gb[c + 1]);
    *(ushort2*)(hp + c) = o;
  }
}

// ---------------- tiled bf16 MFMA GEMM: C = A[M][K] @ Bt[N][K]^T ------------
// BM=256, BN=128, 4 waves (each 128M x 64N = 8x4 frags), BK=32.
// Triple-buffered LDS (A 3x16KB, B 3x8KB = 72KB) with counted vmcnt:
// 2 K-tiles always in flight; raw s_barrier (no implicit drain).
// LDS swizzle: 2-row (128B) units, slot = ((row&1)*4+g) ^ (unit&7), applied
// on the global SOURCE address (LDS stays linear for global_load_lds).
// EPI: 0=QKV scatter (q scaled, v transposed), 1=proj+unshift+residual->f32,
//      2=FC1+GELU->bf16, 3=FC2+residual->f32 out (in-place aux==of32 ok)
template <int EPI, int KDIM>
__global__ __launch_bounds__(256, 2) void k_gemm(
    const short* __restrict__ A, const short* __restrict__ Bt,
    const float* __restrict__ bias, short* __restrict__ ob0,
    short* __restrict__ ob1, short* __restrict__ ob2,
    const float* __restrict__ aux, float* __restrict__ of32) {
  __shared__ short As[24576];   // 3 bufs x [256 rows][32 k] (8192 shorts each)
  __shared__ short Bs[12288];   // 3 bufs x [128 rows][32 k] (4096 shorts each)
  const int tid = threadIdx.x;
  const int wave = tid >> 6, lane = tid & 63;
  const int g = lane >> 4, li = lane & 15;

  // T1: bijective XCD-chunked swizzle (nwg % 8 == 0 for all our launches)
  const int nx = gridDim.x;
  const int nwg = nx * gridDim.y;
  int bid = blockIdx.y * nx + blockIdx.x;
  const int cpx = nwg >> 3;
  bid = (bid & 7) * cpx + (bid >> 3);
  const int m0 = (bid / nx) << 8, n0 = (bid % nx) << 7;

  // ---- staging addressing (per thread): LDS byte t*16 of each 4KB chunk ----
  const int u_ = tid >> 3;                 // 2-row unit within chunk (0..31)
  const int s_ = tid & 7;                  // 16B slot within unit
  const int sx = s_ ^ (u_ & 7);            // inverse swizzle on source
  const int srow = (u_ << 1) + (sx >> 2);  // source row within chunk (0..63)
  const int scol = (sx & 3) << 3;          // source col (shorts)
  const short* gAs = A + (size_t)(m0 + srow) * KDIM + scol;
  const short* gBs = Bt + (size_t)(n0 + srow) * KDIM + scol;
  short* lAs = As + wave * 512;            // + buf*8192 + p*2048
  short* lBs = Bs + wave * 512;            // + buf*4096 + p*2048

  // ---- fragment read addressing ----
  const int wm = wave >> 1, wn = wave & 1;
  const int li2 = li >> 1;
  const int slot = (((li & 1) << 2) + g) ^ li2;     // li2 in 0..7
  const int abase = wm * 4096 + li2 * 64 + slot * 8;
  const int bbase = wn * 2048 + li2 * 64 + slot * 8;

  f32x4 acc[8][4] = {};

#define STAGE(buf, kt)                                                        \
  do {                                                                        \
    _Pragma("unroll") for (int p = 0; p < 4; p++)                             \
        gload_lds16(gAs + (size_t)(p * 64) * KDIM + (kt),                     \
                    lAs + (buf) * 8192 + p * 2048);                           \
    _Pragma("unroll") for (int p = 0; p < 2; p++)                             \
        gload_lds16(gBs + (size_t)(p * 64) * KDIM + (kt),                     \
                    lBs + (buf) * 4096 + p * 2048);                           \
  } while (0)

#define COMPUTE(buf)                                                          \
  do {                                                                        \
    const short* pa = As + (buf) * 8192 + abase;                              \
    const short* pb = Bs + (buf) * 4096 + bbase;                              \
    bf16x8_t a[8], b[4];                                                      \
    _Pragma("unroll") for (int mi = 0; mi < 8; mi++)                          \
        a[mi] = *(const bf16x8_t*)(pa + mi * 512);                            \
    _Pragma("unroll") for (int ni = 0; ni < 4; ni++)                          \
        b[ni] = *(const bf16x8_t*)(pb + ni * 512);                            \
    _Pragma("unroll") for (int mi = 0; mi < 8; mi++)                          \
        _Pragma("unroll") for (int ni = 0; ni < 4; ni++) acc[mi][ni] =        \
        __builtin_amdgcn_mfma_f32_16x16x32_bf16(a[mi], b[ni], acc[mi][ni],    \
                                                0, 0, 0);                     \
  } while (0)

  constexpr int NT = KDIM / 32;
  STAGE(0, 0);
  STAGE(1, 32);
#pragma unroll 3
  for (int t = 0; t < NT; ++t) {
    asm volatile("s_waitcnt lgkmcnt(0)" ::: "memory");
    __builtin_amdgcn_s_barrier();        // prev reads done -> safe to overwrite
    if (t + 2 < NT) {
      STAGE((t + 2) % 3, (t + 2) * 32);
      asm volatile("s_waitcnt vmcnt(12)" ::: "memory");  // tile t landed
    } else if (t + 1 < NT) {
      asm volatile("s_waitcnt vmcnt(6)" ::: "memory");
    } else {
      asm volatile("s_waitcnt vmcnt(0)" ::: "memory");
    }
    __builtin_amdgcn_s_barrier();        // buf t%3 staged for all waves
    COMPUTE(t % 3);
  }
#undef STAGE
#undef COMPUTE

  // epilogue: row = m0 + wm*128 + mi*16 + g*4 + r ; col = n0 + wn*64 + ni*16 + li
#pragma unroll
  for (int mi = 0; mi < 8; mi++) {
#pragma unroll
    for (int ni = 0; ni < 4; ni++) {
      const int col = n0 + wn * 64 + ni * 16 + li;
      const float bc = bias[col];
      const int rbase = m0 + wm * 128 + mi * 16 + g * 4;
      if constexpr (EPI == 0) {
        const int s = col / 384;
        const int rem = col - s * 384;
        const int head = rem >> 5, d = rem & 31;
#pragma unroll
        for (int r = 0; r < 4; r++) {
          const int row = rbase + r;
          const int widx = row >> 6, n = row & 63;
          float v = acc[mi][ni][r] + bc;
          if (s == 0)
            ob0[(((size_t)widx * 12 + head) * 64 + n) * 32 + d] =
                f2bf(v * 0.17677669529663687f);  // fold q scale (32^-1/2)
          else if (s == 1)
            ob1[(((size_t)widx * 12 + head) * 64 + n) * 32 + d] = f2bf(v);
          else  // v stored transposed: [widx][head][d][n]
            ob2[(((size_t)widx * 12 + head) * 32 + d) * 64 + n] = f2bf(v);
        }
      } else if constexpr (EPI == 1) {
#pragma unroll
        for (int r = 0; r < 4; r++) {
          const int row = rbase + r;
          const int widx = row >> 6, n = row & 63;
          const int wloc = widx & 255, bb = widx >> 8;
          const int z = ((wloc >> 6) << 2) + (n >> 4);
          const int h = (((wloc >> 3) & 7) << 2) + ((n >> 2) & 3);
          const int w = ((wloc & 7) << 2) + (n & 3);
          const int zs = (z + 2) & 15, hs = (h + 2) & 31, wsx = (w + 2) & 31;
          const size_t t = (size_t)bb * 16384 + zs * 1024 + hs * 32 + wsx;
          of32[t * 384 + col] = aux[t * 384 + col] + acc[mi][ni][r] + bc;
        }
      } else if constexpr (EPI == 2) {
#pragma unroll
        for (int r = 0; r < 4; r++) {
          const int row = rbase + r;
          float v = acc[mi][ni][r] + bc;
          ob0[(size_t)row * 1536 + col] =
              f2bf(0.5f * v * (1.f + erff(v * 0.70710678118654752f)));
        }
      } else {
#pragma unroll
        for (int r = 0; r < 4; r++) {
          const int row = rbase + r;
          of32[(size_t)row * 384 + col] =
              aux[(size_t)row * 384 + col] + acc[mi][ni][r] + bc;
        }
      }
    }
  }
}

// ---------------- windowed attention: 4 waves/block, 1 wave per (win,head) --
__global__ __launch_bounds__(256) void k_attn(
    const short* __restrict__ qb, const short* __restrict__ kb,
    const short* __restrict__ vb, const float* __restrict__ relb,
    short* __restrict__ owin) {
  __shared__ short pt[4][5120];  // per-wave [qn][kn], stride 80
  const int wave = threadIdx.x >> 6;
  const int wh_ = blockIdx.x * 4 + wave;   // widx*12 + head
  const int widx = wh_ / 12, head = wh_ - widx * 12;
  const int lane = threadIdx.x & 63;
  const int g = lane >> 4, li = lane & 15;
  const short* qp = qb + (size_t)wh_ * 2048;
  const short* kp = kb + (size_t)wh_ * 2048;
  const short* vp = vb + (size_t)wh_ * 2048;  // [d][n] layout
  short* ptw = pt[wave];
  bf16x8_t kf[4], qf[4];
#pragma unroll
  for (int t = 0; t < 4; t++) {
    kf[t] = *(const bf16x8_t*)(kp + (t * 16 + li) * 32 + g * 8);
    qf[t] = *(const bf16x8_t*)(qp + (t * 16 + li) * 32 + g * 8);
  }
  f32x4 zero = {0.f, 0.f, 0.f, 0.f};
  f32x4 st[4][4];  // [ti: kn-block][tj: qn-block]
#pragma unroll
  for (int ti = 0; ti < 4; ti++)
#pragma unroll
    for (int tj = 0; tj < 4; tj++)
      st[ti][tj] = __builtin_amdgcn_mfma_f32_16x16x32_bf16(kf[ti], qf[tj], zero, 0, 0, 0);
  const int wloc = widx & 255;
  const int wz = wloc >> 6, wh2 = (wloc >> 3) & 7, ww2 = wloc & 7;
#pragma unroll
  for (int tj = 0; tj < 4; tj++) {
    const int qn = tj * 16 + li;
    const int qz = qn >> 4, qh = (qn >> 2) & 3, qw = qn & 3;
    const int cq = ((wz < 3) ? 0 : ((qz < 2) ? 1 : 2)) * 9 +
                   ((wh2 < 7) ? 0 : ((qh < 2) ? 1 : 2)) * 3 +
                   ((ww2 < 7) ? 0 : ((qw < 2) ? 1 : 2));
    float mx = -1e30f;
#pragma unroll
    for (int ti = 0; ti < 4; ti++) {
#pragma unroll
      for (int r = 0; r < 4; r++) {
        const int kn = ti * 16 + g * 4 + r;
        const int kz = kn >> 4, kh = (kn >> 2) & 3, kw = kn & 3;
        const int ck = ((wz < 3) ? 0 : ((kz < 2) ? 1 : 2)) * 9 +
                       ((wh2 < 7) ? 0 : ((kh < 2) ? 1 : 2)) * 3 +
                       ((ww2 < 7) ? 0 : ((kw < 2) ? 1 : 2));
        const int idx = (qz - kz + 3) * 49 + (qh - kh + 3) * 7 + (qw - kw + 3);
        float v = st[ti][tj][r] + relb[idx * 12 + head] + ((ck == cq) ? 0.f : -100.f);
        st[ti][tj][r] = v;
        mx = fmaxf(mx, v);
      }
    }
    mx = fmaxf(mx, __shfl_xor(mx, 16));
    mx = fmaxf(mx, __shfl_xor(mx, 32));
    float sum = 0.f;
#pragma unroll
    for (int ti = 0; ti < 4; ti++)
#pragma unroll
      for (int r = 0; r < 4; r++) {
        float e = __expf(st[ti][tj][r] - mx);
        st[ti][tj][r] = e;
        sum += e;
      }
    sum += __shfl_xor(sum, 16);
    sum += __shfl_xor(sum, 32);
    const float rs = 1.f / sum;
#pragma unroll
    for (int ti = 0; ti < 4; ti++)
#pragma unroll
      for (int r = 0; r < 4; r++)
        ptw[qn * 80 + ti * 16 + g * 4 + r] = f2bf(st[ti][tj][r] * rs);
  }
  __syncthreads();
  f32x4 o[4][2] = {};
#pragma unroll
  for (int kb2 = 0; kb2 < 2; kb2++) {
    bf16x8_t pa[4], bv[2];
#pragma unroll
    for (int tq = 0; tq < 4; tq++)
      pa[tq] = *(const bf16x8_t*)(ptw + (tq * 16 + li) * 80 + kb2 * 32 + g * 8);
#pragma unroll
    for (int td = 0; td < 2; td++)
      bv[td] = *(const bf16x8_t*)(vp + (td * 16 + li) * 64 + kb2 * 32 + g * 8);
#pragma unroll
    for (int tq = 0; tq < 4; tq++)
#pragma unroll
      for (int td = 0; td < 2; td++)
        o[tq][td] = __builtin_amdgcn_mfma_f32_16x16x32_bf16(pa[tq], bv[td], o[tq][td], 0, 0, 0);
  }
#pragma unroll
  for (int tq = 0; tq < 4; tq++)
#pragma unroll
    for (int td = 0; td < 2; td++)
#pragma unroll
      for (int r = 0; r < 4; r++) {
        const int qn = tq * 16 + g * 4 + r;
        const int d = td * 16 + li;
        owin[((size_t)widx * 64 + qn) * 384 + head * 32 + d] = f2bf(o[tq][td][r]);
      }
}

// ---------------------------------------------------------------------------
extern "C" void kernel_launch(void* const* d_in, const int* in_sizes, int n_in,
                              void* d_out, int out_size, void* d_ws,
                              size_t ws_size, hipStream_t stream) {
  (void)in_sizes; (void)n_in; (void)out_size; (void)ws_size;
  const float* x      = (const float*)d_in[0];
  const float* n1g    = (const float*)d_in[1];
  const float* n1b    = (const float*)d_in[2];
  const float* qkv_w  = (const float*)d_in[3];
  const float* qkv_b  = (const float*)d_in[4];
  const float* proj_w = (const float*)d_in[5];
  const float* proj_b = (const float*)d_in[6];
  const float* relb   = (const float*)d_in[7];
  const float* n2g    = (const float*)d_in[8];
  const float* n2b    = (const float*)d_in[9];
  const float* fc1_w  = (const float*)d_in[10];
  const float* fc1_b  = (const float*)d_in[11];
  const float* fc2_w  = (const float*)d_in[12];
  const float* fc2_b  = (const float*)d_in[13];
  float* out = (float*)d_out;
  char* ws = (char*)d_ws;

  short* qbuf = (short*)(ws + OFF_Q);
  short* kbuf = (short*)(ws + OFF_K);
  short* vbuf = (short*)(ws + OFF_V);
  short* hid  = (short*)(ws + OFF_HID);
  short* win  = (short*)(ws + OFF_WIN);   // shared: win -> owin -> h2
  short* owin = (short*)(ws + OFF_WIN);
  short* h2   = (short*)(ws + OFF_WIN);
  float* x2   = out;                      // fp32 residual lives in d_out
  short* wq   = (short*)(ws + OFF_WQ);
  short* wp   = (short*)(ws + OFF_WP);
  short* w1   = (short*)(ws + OFF_W1);
  short* w2   = (short*)(ws + OFF_W2);

  // weights -> bf16 transposed [N][K]
  k_w2bf_t<<<(384 * 1152 + 255) / 256, 256, 0, stream>>>(qkv_w, wq, 384, 1152);
  k_w2bf_t<<<(384 * 384 + 255) / 256, 256, 0, stream>>>(proj_w, wp, 384, 384);
  k_w2bf_t<<<(384 * 1536 + 255) / 256, 256, 0, stream>>>(fc1_w, w1, 384, 1536);
  k_w2bf_t<<<(1536 * 384 + 255) / 256, 256, 0, stream>>>(fc2_w, w2, 1536, 384);

  // LN1 + shift + window partition
  k_ln1_window<<<16384, 256, 0, stream>>>(x, n1g, n1b, win);
  // QKV GEMM [65536,384]@[384,1152]
  k_gemm<0, 384><<<dim3(9, 256), 256, 0, stream>>>(win, wq, qkv_b, qbuf, kbuf,
                                                   vbuf, nullptr, nullptr);
  // windowed attention (4 window-heads per block)
  k_attn<<<3072, 256, 0, stream>>>(qbuf, kbuf, vbuf, relb, owin);
  // proj GEMM + unshift + residual -> x2 (in d_out)
  k_gemm<1, 384><<<dim3(3, 256), 256, 0, stream>>>(owin, wp, proj_b, nullptr,
                                                   nullptr, nullptr, x, x2);
  // LN2
  k_ln2<<<16384, 256, 0, stream>>>(x2, n2g, n2b, h2);
  // FC1 + GELU
  k_gemm<2, 384><<<dim3(12, 256), 256, 0, stream>>>(h2, w1, fc1_b, hid, nullptr,
                                                    nullptr, nullptr, nullptr);
  // FC2 + residual -> out (in-place: aux == of32 == d_out)
  k_gemm<3, 1536><<<dim3(3, 256), 256, 0, stream>>>(hid, w2, fc2_b, nullptr,
                                                    nullptr, nullptr, x2, out);
}

// Round 5
// 700.548 us; speedup vs baseline: 1.1490x; 1.1405x over previous
//
#include <hip/hip_runtime.h>
#include <hip/hip_bf16.h>
#include <cstdint>
#include <cmath>

// ---------------------------------------------------------------------------
// Swin3D block: LN1 -> shift+window -> QKV -> win-attn(+relbias+mask) -> proj
//               -> unshift+residual -> LN2 -> FC1+GELU -> FC2 -> +residual
// v4: GEMM BM=256 x BN=128, BK=32, triple-buffered LDS + counted vmcnt (T4),
//     XCD swizzle (T1), LDS-swizzled staging (T2). NEW: LDS-staged coalesced
//     epilogue stores for bf16 outputs (QKV incl. V-transpose, FC1) and
//     tanh-GELU instead of erff.
// ---------------------------------------------------------------------------

typedef __attribute__((ext_vector_type(4))) float f32x4;
typedef __attribute__((ext_vector_type(4))) int i32x4;
typedef __attribute__((ext_vector_type(8))) __bf16 bf16x8_t;

static __device__ __forceinline__ short f2bf(float f) {
  unsigned u = __builtin_bit_cast(unsigned, f);
  unsigned lsb = (u >> 16) & 1u;
  u += 0x7fffu + lsb;
  return (short)(u >> 16);
}

static __device__ __forceinline__ float fgelu(float x) {
  float u = 0.7978845608028654f * x * (1.f + 0.044715f * x * x);
  float e = __expf(2.f * u);
  float t = 1.f - 2.f / (e + 1.f);   // tanh(u)
  return 0.5f * x * (1.f + t);
}

static __device__ __forceinline__ void gload_lds16(const short* g, short* l) {
  __builtin_amdgcn_global_load_lds(
      (const __attribute__((address_space(1))) void*)g,
      (__attribute__((address_space(3))) void*)l, 16, 0, 0);
}

// ---------------- workspace layout (bytes), total ~255.2 MB ----------------
static constexpr size_t OFF_Q    = 0;
static constexpr size_t OFF_K    = 50331648;
static constexpr size_t OFF_V    = 100663296;                // qkv end 150994944
static constexpr size_t OFF_HID  = 0;                        // over dead q/k/v
static constexpr size_t OFF_WIN  = 201326592;                // win / owin / h2 share
static constexpr size_t OFF_WQ   = OFF_WIN + 50331648;       // wqkv^T [1152][384]
static constexpr size_t OFF_WP   = OFF_WQ  + 884736;         // wproj^T [384][384]
static constexpr size_t OFF_W1   = OFF_WP  + 294912;         // wfc1^T [1536][384]
static constexpr size_t OFF_W2   = OFF_W1  + 1179648;        // wfc2^T [384][1536]

// ---------------- weight fp32 -> bf16 transpose ----------------
__global__ void k_w2bf_t(const float* __restrict__ w, short* __restrict__ wt,
                         int K, int N) {
  int idx = blockIdx.x * 256 + threadIdx.x;
  if (idx >= K * N) return;
  int k = idx / N, n = idx - k * N;
  wt[(size_t)n * K + k] = f2bf(w[idx]);
}

// ---------------- LN1 + roll(-2,-2,-2) + window partition -> bf16 ----------
__global__ __launch_bounds__(256) void k_ln1_window(
    const float* __restrict__ x, const float* __restrict__ gw,
    const float* __restrict__ gb, short* __restrict__ win) {
  int slot = blockIdx.x * 4 + (threadIdx.x >> 6);   // widx*64 + n, 0..65535
  int lane = threadIdx.x & 63;
  int widx = slot >> 6, n = slot & 63;
  int bidx = widx >> 8, wloc = widx & 255;
  int z = ((wloc >> 6) << 2) + (n >> 4);
  int h = (((wloc >> 3) & 7) << 2) + ((n >> 2) & 3);
  int w = ((wloc & 7) << 2) + (n & 3);
  int zs = (z + 2) & 15, hs = (h + 2) & 31, ws = (w + 2) & 31;
  const float* xp = x + ((size_t)bidx * 16384 + zs * 1024 + hs * 32 + ws) * 384;
  float2 u[3]; float s = 0.f, s2 = 0.f;
#pragma unroll
  for (int j = 0; j < 3; j++) {
    u[j] = *(const float2*)(xp + lane * 2 + j * 128);
    s += u[j].x + u[j].y; s2 += u[j].x * u[j].x + u[j].y * u[j].y;
  }
#pragma unroll
  for (int o = 1; o < 64; o <<= 1) { s += __shfl_xor(s, o); s2 += __shfl_xor(s2, o); }
  float mu = s * (1.f / 384.f);
  float rinv = rsqrtf(s2 * (1.f / 384.f) - mu * mu + 1e-5f);
  short* wp = win + (size_t)slot * 384;
#pragma unroll
  for (int j = 0; j < 3; j++) {
    int c = lane * 2 + j * 128;
    ushort2 o;
    o.x = (unsigned short)f2bf((u[j].x - mu) * rinv * gw[c] + gb[c]);
    o.y = (unsigned short)f2bf((u[j].y - mu) * rinv * gw[c + 1] + gb[c + 1]);
    *(ushort2*)(wp + c) = o;
  }
}

// ---------------- LN2 (plain, token order) -> bf16 ----------------
__global__ __launch_bounds__(256) void k_ln2(
    const float* __restrict__ x2, const float* __restrict__ gw,
    const float* __restrict__ gb, short* __restrict__ h2) {
  int t = blockIdx.x * 4 + (threadIdx.x >> 6);
  int lane = threadIdx.x & 63;
  const float* xp = x2 + (size_t)t * 384;
  float2 u[3]; float s = 0.f, s2 = 0.f;
#pragma unroll
  for (int j = 0; j < 3; j++) {
    u[j] = *(const float2*)(xp + lane * 2 + j * 128);
    s += u[j].x + u[j].y; s2 += u[j].x * u[j].x + u[j].y * u[j].y;
  }
#pragma unroll
  for (int o = 1; o < 64; o <<= 1) { s += __shfl_xor(s, o); s2 += __shfl_xor(s2, o); }
  float mu = s * (1.f / 384.f);
  float rinv = rsqrtf(s2 * (1.f / 384.f) - mu * mu + 1e-5f);
  short* hp = h2 + (size_t)t * 384;
#pragma unroll
  for (int j = 0; j < 3; j++) {
    int c = lane * 2 + j * 128;
    ushort2 o;
    o.x = (unsigned short)f2bf((u[j].x - mu) * rinv * gw[c] + gb[c]);
    o.y = (unsigned short)f2bf((u[j].y - mu) * rinv * gw[c + 1] + gb[c + 1]);
    *(ushort2*)(hp + c) = o;
  }
}

// ---------------- tiled bf16 MFMA GEMM: C = A[M][K] @ Bt[N][K]^T ------------
// BM=256, BN=128, 4 waves (each 128M x 64N = 8x4 frags), BK=32.
// Triple-buffered LDS, counted vmcnt, raw s_barrier, source-side row swizzle.
// EPI 0 (QKV) / 2 (FC1): LDS-staged coalesced stores (16B chunks, XOR swz).
// EPI 1 (proj+residual->f32), 3 (FC2+residual->f32): direct stores.
template <int EPI, int KDIM>
__global__ __launch_bounds__(256, 2) void k_gemm(
    const short* __restrict__ A, const short* __restrict__ Bt,
    const float* __restrict__ bias, short* __restrict__ ob0,
    short* __restrict__ ob1, short* __restrict__ ob2,
    const float* __restrict__ aux, float* __restrict__ of32) {
  __shared__ short smem[36864];            // 72 KB: As 24576 | Bs 12288
  short* As = smem;                        // 3 bufs x [256 rows][32 k]
  short* Bs = smem + 24576;                // 3 bufs x [128 rows][32 k]
  const int tid = threadIdx.x;
  const int wave = tid >> 6, lane = tid & 63;
  const int g = lane >> 4, li = lane & 15;

  // T1: bijective XCD-chunked swizzle (nwg % 8 == 0 for all our launches)
  const int nx = gridDim.x;
  const int nwg = nx * gridDim.y;
  int bid = blockIdx.y * nx + blockIdx.x;
  const int cpx = nwg >> 3;
  bid = (bid & 7) * cpx + (bid >> 3);
  const int m0 = (bid / nx) << 8, n0 = (bid % nx) << 7;

  // ---- staging addressing ----
  const int u_ = tid >> 3;                 // 2-row unit within chunk (0..31)
  const int s_ = tid & 7;                  // 16B slot within unit
  const int sx = s_ ^ (u_ & 7);            // inverse swizzle on source
  const int srow = (u_ << 1) + (sx >> 2);  // source row within chunk (0..63)
  const int scol = (sx & 3) << 3;          // source col (shorts)
  const short* gAs = A + (size_t)(m0 + srow) * KDIM + scol;
  const short* gBs = Bt + (size_t)(n0 + srow) * KDIM + scol;
  short* lAs = As + wave * 512;            // + buf*8192 + p*2048
  short* lBs = Bs + wave * 512;            // + buf*4096 + p*2048

  // ---- fragment read addressing ----
  const int wm = wave >> 1, wn = wave & 1;
  const int li2 = li >> 1;
  const int slot = (((li & 1) << 2) + g) ^ li2;
  const int abase = wm * 4096 + li2 * 64 + slot * 8;
  const int bbase = wn * 2048 + li2 * 64 + slot * 8;

  f32x4 acc[8][4] = {};

#define STAGE(buf, kt)                                                        \
  do {                                                                        \
    _Pragma("unroll") for (int p = 0; p < 4; p++)                             \
        gload_lds16(gAs + (size_t)(p * 64) * KDIM + (kt),                     \
                    lAs + (buf) * 8192 + p * 2048);                           \
    _Pragma("unroll") for (int p = 0; p < 2; p++)                             \
        gload_lds16(gBs + (size_t)(p * 64) * KDIM + (kt),                     \
                    lBs + (buf) * 4096 + p * 2048);                           \
  } while (0)

#define COMPUTE(buf)                                                          \
  do {                                                                        \
    const short* pa = As + (buf) * 8192 + abase;                              \
    const short* pb = Bs + (buf) * 4096 + bbase;                              \
    bf16x8_t a[8], b[4];                                                      \
    _Pragma("unroll") for (int mi = 0; mi < 8; mi++)                          \
        a[mi] = *(const bf16x8_t*)(pa + mi * 512);                            \
    _Pragma("unroll") for (int ni = 0; ni < 4; ni++)                          \
        b[ni] = *(const bf16x8_t*)(pb + ni * 512);                            \
    _Pragma("unroll") for (int mi = 0; mi < 8; mi++)                          \
        _Pragma("unroll") for (int ni = 0; ni < 4; ni++) acc[mi][ni] =        \
        __builtin_amdgcn_mfma_f32_16x16x32_bf16(a[mi], b[ni], acc[mi][ni],    \
                                                0, 0, 0);                     \
  } while (0)

  constexpr int NT = KDIM / 32;
  STAGE(0, 0);
  STAGE(1, 32);
#pragma unroll 3
  for (int t = 0; t < NT; ++t) {
    asm volatile("s_waitcnt lgkmcnt(0)" ::: "memory");
    __builtin_amdgcn_s_barrier();        // prev reads done -> safe to overwrite
    if (t + 2 < NT) {
      STAGE((t + 2) % 3, (t + 2) * 32);
      asm volatile("s_waitcnt vmcnt(12)" ::: "memory");  // tile t landed
    } else if (t + 1 < NT) {
      asm volatile("s_waitcnt vmcnt(6)" ::: "memory");
    } else {
      asm volatile("s_waitcnt vmcnt(0)" ::: "memory");
    }
    __builtin_amdgcn_s_barrier();        // buf t%3 staged for all waves
    COMPUTE(t % 3);
  }
#undef STAGE
#undef COMPUTE

  // epilogue: local row = wm*128+mi*16+g*4+r ; local col = wn*64+ni*16+li
  if constexpr (EPI == 0 || EPI == 2) {
    // ---- LDS-staged coalesced stores ----
    __syncthreads();                       // all K-loop LDS reads retired
    short* ct = smem;                      // 32768-short C tile, global layout
    const int s = (EPI == 0) ? (n0 / 384) : 0;   // block-uniform q/k/v select
    const float scale =
        (EPI == 0 && s == 0) ? 0.17677669529663687f : 1.f;
#pragma unroll
    for (int mi = 0; mi < 8; mi++) {
#pragma unroll
      for (int ni = 0; ni < 4; ni++) {
        const int colc = wn * 64 + ni * 16 + li;
        const float bc = bias[n0 + colc];
#pragma unroll
        for (int r = 0; r < 4; r++) {
          const int row = wm * 128 + mi * 16 + g * 4 + r;
          float v = acc[mi][ni][r] + bc;
          int idx16, sub;
          if constexpr (EPI == 0) {
            const int hh = colc >> 5, d = colc & 31;
            const int widx_l = row >> 6, n = row & 63;
            const int run = widx_l * 4 + hh;
            if (s < 2) {                   // q/k: [w][h][n][d]
              idx16 = run * 256 + n * 4 + (d >> 3);
              idx16 ^= (idx16 >> 4) & 7;
              sub = d & 7;
            } else {                       // v: [w][h][d][n]
              idx16 = run * 256 + d * 8 + (n >> 3);
              idx16 ^= (idx16 >> 3) & 7;
              sub = n & 7;
            }
            v *= scale;
          } else {                         // FC1: row-major [256][128]
            idx16 = row * 16 + (colc >> 3);
            idx16 ^= (idx16 >> 4) & 7;
            sub = colc & 7;
            v = fgelu(v);
          }
          ct[idx16 * 8 + sub] = f2bf(v);
        }
      }
    }
    __syncthreads();
    if constexpr (EPI == 0) {
      const int hb = (n0 % 384) >> 5;
      const int wg0 = m0 >> 6;
      short* dst = (s == 0) ? ob0 : (s == 1) ? ob1 : ob2;
#pragma unroll
      for (int k2 = 0; k2 < 16; k2++) {
        const int c = k2 * 256 + tid;
        const int cs = (s < 2) ? (c ^ ((c >> 4) & 7)) : (c ^ ((c >> 3) & 7));
        i32x4 val = *(const i32x4*)(ct + cs * 8);
        const int run = c >> 8, sub2 = c & 255;
        short* gp = dst +
                    ((size_t)(wg0 + (run >> 2)) * 12 + hb + (run & 3)) * 2048 +
                    sub2 * 8;
        *(i32x4*)gp = val;
      }
    } else {
#pragma unroll
      for (int k2 = 0; k2 < 16; k2++) {
        const int c = k2 * 256 + tid;
        const int cs = c ^ ((c >> 4) & 7);
        i32x4 val = *(const i32x4*)(ct + cs * 8);
        const int row = c >> 4;
        short* gp = ob0 + (size_t)(m0 + row) * 1536 + n0 + (c & 15) * 8;
        *(i32x4*)gp = val;
      }
    }
  } else {
#pragma unroll
    for (int mi = 0; mi < 8; mi++) {
#pragma unroll
      for (int ni = 0; ni < 4; ni++) {
        const int col = n0 + wn * 64 + ni * 16 + li;
        const float bc = bias[col];
        const int rbase = m0 + wm * 128 + mi * 16 + g * 4;
        if constexpr (EPI == 1) {
#pragma unroll
          for (int r = 0; r < 4; r++) {
            const int row = rbase + r;
            const int widx = row >> 6, n = row & 63;
            const int wloc = widx & 255, bb = widx >> 8;
            const int z = ((wloc >> 6) << 2) + (n >> 4);
            const int h = (((wloc >> 3) & 7) << 2) + ((n >> 2) & 3);
            const int w = ((wloc & 7) << 2) + (n & 3);
            const int zs = (z + 2) & 15, hs = (h + 2) & 31, wsx = (w + 2) & 31;
            const size_t t = (size_t)bb * 16384 + zs * 1024 + hs * 32 + wsx;
            of32[t * 384 + col] = aux[t * 384 + col] + acc[mi][ni][r] + bc;
          }
        } else {
#pragma unroll
          for (int r = 0; r < 4; r++) {
            const int row = rbase + r;
            of32[(size_t)row * 384 + col] =
                aux[(size_t)row * 384 + col] + acc[mi][ni][r] + bc;
          }
        }
      }
    }
  }
}

// ---------------- windowed attention: 4 waves/block, 1 wave per (win,head) --
__global__ __launch_bounds__(256) void k_attn(
    const short* __restrict__ qb, const short* __restrict__ kb,
    const short* __restrict__ vb, const float* __restrict__ relb,
    short* __restrict__ owin) {
  __shared__ short pt[4][5120];  // per-wave [qn][kn], stride 80
  const int wave = threadIdx.x >> 6;
  const int wh_ = blockIdx.x * 4 + wave;   // widx*12 + head
  const int widx = wh_ / 12, head = wh_ - widx * 12;
  const int lane = threadIdx.x & 63;
  const int g = lane >> 4, li = lane & 15;
  const short* qp = qb + (size_t)wh_ * 2048;
  const short* kp = kb + (size_t)wh_ * 2048;
  const short* vp = vb + (size_t)wh_ * 2048;  // [d][n] layout
  short* ptw = pt[wave];
  bf16x8_t kf[4], qf[4];
#pragma unroll
  for (int t = 0; t < 4; t++) {
    kf[t] = *(const bf16x8_t*)(kp + (t * 16 + li) * 32 + g * 8);
    qf[t] = *(const bf16x8_t*)(qp + (t * 16 + li) * 32 + g * 8);
  }
  f32x4 zero = {0.f, 0.f, 0.f, 0.f};
  f32x4 st[4][4];  // [ti: kn-block][tj: qn-block]
#pragma unroll
  for (int ti = 0; ti < 4; ti++)
#pragma unroll
    for (int tj = 0; tj < 4; tj++)
      st[ti][tj] = __builtin_amdgcn_mfma_f32_16x16x32_bf16(kf[ti], qf[tj], zero, 0, 0, 0);
  const int wloc = widx & 255;
  const int wz = wloc >> 6, wh2 = (wloc >> 3) & 7, ww2 = wloc & 7;
#pragma unroll
  for (int tj = 0; tj < 4; tj++) {
    const int qn = tj * 16 + li;
    const int qz = qn >> 4, qh = (qn >> 2) & 3, qw = qn & 3;
    const int cq = ((wz < 3) ? 0 : ((qz < 2) ? 1 : 2)) * 9 +
                   ((wh2 < 7) ? 0 : ((qh < 2) ? 1 : 2)) * 3 +
                   ((ww2 < 7) ? 0 : ((qw < 2) ? 1 : 2));
    float mx = -1e30f;
#pragma unroll
    for (int ti = 0; ti < 4; ti++) {
#pragma unroll
      for (int r = 0; r < 4; r++) {
        const int kn = ti * 16 + g * 4 + r;
        const int kz = kn >> 4, kh = (kn >> 2) & 3, kw = kn & 3;
        const int ck = ((wz < 3) ? 0 : ((kz < 2) ? 1 : 2)) * 9 +
                       ((wh2 < 7) ? 0 : ((kh < 2) ? 1 : 2)) * 3 +
                       ((ww2 < 7) ? 0 : ((kw < 2) ? 1 : 2));
        const int idx = (qz - kz + 3) * 49 + (qh - kh + 3) * 7 + (qw - kw + 3);
        float v = st[ti][tj][r] + relb[idx * 12 + head] + ((ck == cq) ? 0.f : -100.f);
        st[ti][tj][r] = v;
        mx = fmaxf(mx, v);
      }
    }
    mx = fmaxf(mx, __shfl_xor(mx, 16));
    mx = fmaxf(mx, __shfl_xor(mx, 32));
    float sum = 0.f;
#pragma unroll
    for (int ti = 0; ti < 4; ti++)
#pragma unroll
      for (int r = 0; r < 4; r++) {
        float e = __expf(st[ti][tj][r] - mx);
        st[ti][tj][r] = e;
        sum += e;
      }
    sum += __shfl_xor(sum, 16);
    sum += __shfl_xor(sum, 32);
    const float rs = 1.f / sum;
#pragma unroll
    for (int ti = 0; ti < 4; ti++)
#pragma unroll
      for (int r = 0; r < 4; r++)
        ptw[qn * 80 + ti * 16 + g * 4 + r] = f2bf(st[ti][tj][r] * rs);
  }
  __syncthreads();
  f32x4 o[4][2] = {};
#pragma unroll
  for (int kb2 = 0; kb2 < 2; kb2++) {
    bf16x8_t pa[4], bv[2];
#pragma unroll
    for (int tq = 0; tq < 4; tq++)
      pa[tq] = *(const bf16x8_t*)(ptw + (tq * 16 + li) * 80 + kb2 * 32 + g * 8);
#pragma unroll
    for (int td = 0; td < 2; td++)
      bv[td] = *(const bf16x8_t*)(vp + (td * 16 + li) * 64 + kb2 * 32 + g * 8);
#pragma unroll
    for (int tq = 0; tq < 4; tq++)
#pragma unroll
      for (int td = 0; td < 2; td++)
        o[tq][td] = __builtin_amdgcn_mfma_f32_16x16x32_bf16(pa[tq], bv[td], o[tq][td], 0, 0, 0);
  }
#pragma unroll
  for (int tq = 0; tq < 4; tq++)
#pragma unroll
    for (int td = 0; td < 2; td++)
#pragma unroll
      for (int r = 0; r < 4; r++) {
        const int qn = tq * 16 + g * 4 + r;
        const int d = td * 16 + li;
        owin[((size_t)widx * 64 + qn) * 384 + head * 32 + d] = f2bf(o[tq][td][r]);
      }
}

// ---------------------------------------------------------------------------
extern "C" void kernel_launch(void* const* d_in, const int* in_sizes, int n_in,
                              void* d_out, int out_size, void* d_ws,
                              size_t ws_size, hipStream_t stream) {
  (void)in_sizes; (void)n_in; (void)out_size; (void)ws_size;
  const float* x      = (const float*)d_in[0];
  const float* n1g    = (const float*)d_in[1];
  const float* n1b    = (const float*)d_in[2];
  const float* qkv_w  = (const float*)d_in[3];
  const float* qkv_b  = (const float*)d_in[4];
  const float* proj_w = (const float*)d_in[5];
  const float* proj_b = (const float*)d_in[6];
  const float* relb   = (const float*)d_in[7];
  const float* n2g    = (const float*)d_in[8];
  const float* n2b    = (const float*)d_in[9];
  const float* fc1_w  = (const float*)d_in[10];
  const float* fc1_b  = (const float*)d_in[11];
  const float* fc2_w  = (const float*)d_in[12];
  const float* fc2_b  = (const float*)d_in[13];
  float* out = (float*)d_out;
  char* ws = (char*)d_ws;

  short* qbuf = (short*)(ws + OFF_Q);
  short* kbuf = (short*)(ws + OFF_K);
  short* vbuf = (short*)(ws + OFF_V);
  short* hid  = (short*)(ws + OFF_HID);
  short* win  = (short*)(ws + OFF_WIN);   // shared: win -> owin -> h2
  short* owin = (short*)(ws + OFF_WIN);
  short* h2   = (short*)(ws + OFF_WIN);
  float* x2   = out;                      // fp32 residual lives in d_out
  short* wq   = (short*)(ws + OFF_WQ);
  short* wp   = (short*)(ws + OFF_WP);
  short* w1   = (short*)(ws + OFF_W1);
  short* w2   = (short*)(ws + OFF_W2);

  // weights -> bf16 transposed [N][K]
  k_w2bf_t<<<(384 * 1152 + 255) / 256, 256, 0, stream>>>(qkv_w, wq, 384, 1152);
  k_w2bf_t<<<(384 * 384 + 255) / 256, 256, 0, stream>>>(proj_w, wp, 384, 384);
  k_w2bf_t<<<(384 * 1536 + 255) / 256, 256, 0, stream>>>(fc1_w, w1, 384, 1536);
  k_w2bf_t<<<(1536 * 384 + 255) / 256, 256, 0, stream>>>(fc2_w, w2, 1536, 384);

  // LN1 + shift + window partition
  k_ln1_window<<<16384, 256, 0, stream>>>(x, n1g, n1b, win);
  // QKV GEMM [65536,384]@[384,1152]
  k_gemm<0, 384><<<dim3(9, 256), 256, 0, stream>>>(win, wq, qkv_b, qbuf, kbuf,
                                                   vbuf, nullptr, nullptr);
  // windowed attention (4 window-heads per block)
  k_attn<<<3072, 256, 0, stream>>>(qbuf, kbuf, vbuf, relb, owin);
  // proj GEMM + unshift + residual -> x2 (in d_out)
  k_gemm<1, 384><<<dim3(3, 256), 256, 0, stream>>>(owin, wp, proj_b, nullptr,
                                                   nullptr, nullptr, x, x2);
  // LN2
  k_ln2<<<16384, 256, 0, stream>>>(x2, n2g, n2b, h2);
  // FC1 + GELU
  k_gemm<2, 384><<<dim3(12, 256), 256, 0, stream>>>(h2, w1, fc1_b, hid, nullptr,
                                                    nullptr, nullptr, nullptr);
  // FC2 + residual -> out (in-place: aux == of32 == d_out)
  k_gemm<3, 1536><<<dim3(3, 256), 256, 0, stream>>>(hid, w2, fc2_b, nullptr,
                                                    nullptr, nullptr, x2, out);
}

// Round 6
// 683.607 us; speedup vs baseline: 1.1775x; 1.0248x over previous
//
#include <hip/hip_runtime.h>
#include <hip/hip_bf16.h>
#include <cstdint>
#include <cmath>

// ---------------------------------------------------------------------------
// Swin3D block. v5: GEMM back to 128x128 tile (64x64/wave, 64-AGPR acc) for
// 3 blocks/CU occupancy; BK=32 double-buffered LDS, counted vmcnt(4), XOR
// swizzle, XCD swizzle. Direct epilogues (q/k/FC1), V staged. exp2-GELU.
// ---------------------------------------------------------------------------

typedef __attribute__((ext_vector_type(4))) float f32x4;
typedef __attribute__((ext_vector_type(4))) int i32x4;
typedef __attribute__((ext_vector_type(8))) __bf16 bf16x8_t;

static __device__ __forceinline__ short f2bf(float f) {
  unsigned u = __builtin_bit_cast(unsigned, f);
  unsigned lsb = (u >> 16) & 1u;
  u += 0x7fffu + lsb;
  return (short)(u >> 16);
}

static __device__ __forceinline__ float fgelu(float x) {
  // x * sigmoid(1.5957691x + 0.07135482x^3), exp folded to exp2
  float xx = x * x;
  float p = __builtin_fmaf(-0.102944499f, xx, -2.302118131f);
  float e = __builtin_amdgcn_exp2f(p * x);
  return x * __builtin_amdgcn_rcpf(1.f + e);
}

static __device__ __forceinline__ void gload_lds16(const short* g, short* l) {
  __builtin_amdgcn_global_load_lds(
      (const __attribute__((address_space(1))) void*)g,
      (__attribute__((address_space(3))) void*)l, 16, 0, 0);
}

// ---------------- workspace layout (bytes), total ~255.2 MB ----------------
static constexpr size_t OFF_Q    = 0;
static constexpr size_t OFF_K    = 50331648;
static constexpr size_t OFF_V    = 100663296;
static constexpr size_t OFF_HID  = 0;                        // over dead q/k/v
static constexpr size_t OFF_WIN  = 201326592;                // win / owin / h2
static constexpr size_t OFF_WQ   = OFF_WIN + 50331648;
static constexpr size_t OFF_WP   = OFF_WQ  + 884736;
static constexpr size_t OFF_W1   = OFF_WP  + 294912;
static constexpr size_t OFF_W2   = OFF_W1  + 1179648;

// ---------------- weight fp32 -> bf16 transpose (constant divisors) --------
template <int K, int N>
__global__ void k_w2bf_t(const float* __restrict__ w, short* __restrict__ wt) {
  int idx = blockIdx.x * 256 + threadIdx.x;
  if (idx >= K * N) return;
  int k = idx / N, n = idx - k * N;
  wt[(size_t)n * K + k] = f2bf(w[idx]);
}

// ---------------- LN1 + roll(-2,-2,-2) + window partition -> bf16 ----------
__global__ __launch_bounds__(256) void k_ln1_window(
    const float* __restrict__ x, const float* __restrict__ gw,
    const float* __restrict__ gb, short* __restrict__ win) {
  int slot = blockIdx.x * 4 + (threadIdx.x >> 6);
  int lane = threadIdx.x & 63;
  int widx = slot >> 6, n = slot & 63;
  int bidx = widx >> 8, wloc = widx & 255;
  int z = ((wloc >> 6) << 2) + (n >> 4);
  int h = (((wloc >> 3) & 7) << 2) + ((n >> 2) & 3);
  int w = ((wloc & 7) << 2) + (n & 3);
  int zs = (z + 2) & 15, hs = (h + 2) & 31, ws = (w + 2) & 31;
  const float* xp = x + ((size_t)bidx * 16384 + zs * 1024 + hs * 32 + ws) * 384;
  float2 u[3]; float s = 0.f, s2 = 0.f;
#pragma unroll
  for (int j = 0; j < 3; j++) {
    u[j] = *(const float2*)(xp + lane * 2 + j * 128);
    s += u[j].x + u[j].y; s2 += u[j].x * u[j].x + u[j].y * u[j].y;
  }
#pragma unroll
  for (int o = 1; o < 64; o <<= 1) { s += __shfl_xor(s, o); s2 += __shfl_xor(s2, o); }
  float mu = s * (1.f / 384.f);
  float rinv = rsqrtf(s2 * (1.f / 384.f) - mu * mu + 1e-5f);
  short* wp = win + (size_t)slot * 384;
#pragma unroll
  for (int j = 0; j < 3; j++) {
    int c = lane * 2 + j * 128;
    ushort2 o;
    o.x = (unsigned short)f2bf((u[j].x - mu) * rinv * gw[c] + gb[c]);
    o.y = (unsigned short)f2bf((u[j].y - mu) * rinv * gw[c + 1] + gb[c + 1]);
    *(ushort2*)(wp + c) = o;
  }
}

// ---------------- LN2 -> bf16 ----------------
__global__ __launch_bounds__(256) void k_ln2(
    const float* __restrict__ x2, const float* __restrict__ gw,
    const float* __restrict__ gb, short* __restrict__ h2) {
  int t = blockIdx.x * 4 + (threadIdx.x >> 6);
  int lane = threadIdx.x & 63;
  const float* xp = x2 + (size_t)t * 384;
  float2 u[3]; float s = 0.f, s2 = 0.f;
#pragma unroll
  for (int j = 0; j < 3; j++) {
    u[j] = *(const float2*)(xp + lane * 2 + j * 128);
    s += u[j].x + u[j].y; s2 += u[j].x * u[j].x + u[j].y * u[j].y;
  }
#pragma unroll
  for (int o = 1; o < 64; o <<= 1) { s += __shfl_xor(s, o); s2 += __shfl_xor(s2, o); }
  float mu = s * (1.f / 384.f);
  float rinv = rsqrtf(s2 * (1.f / 384.f) - mu * mu + 1e-5f);
  short* hp = h2 + (size_t)t * 384;
#pragma unroll
  for (int j = 0; j < 3; j++) {
    int c = lane * 2 + j * 128;
    ushort2 o;
    o.x = (unsigned short)f2bf((u[j].x - mu) * rinv * gw[c] + gb[c]);
    o.y = (unsigned short)f2bf((u[j].y - mu) * rinv * gw[c + 1] + gb[c + 1]);
    *(ushort2*)(hp + c) = o;
  }
}

// ---------------- tiled bf16 MFMA GEMM: C = A[M][K] @ Bt[N][K]^T ------------
// 128x128 tile, 4 waves each 64x64 (acc 64 AGPR), BK=32, double-buffered LDS
// (32 KB), counted vmcnt(4), raw s_barrier, row-pair XOR swizzle both sides.
template <int EPI, int KDIM>
__global__ __launch_bounds__(256, 3) void k_gemm(
    const short* __restrict__ A, const short* __restrict__ Bt,
    const float* __restrict__ bias, short* __restrict__ ob0,
    short* __restrict__ ob1, short* __restrict__ ob2,
    const float* __restrict__ aux, float* __restrict__ of32) {
  __shared__ short smem[16384];           // As 2x4096 | Bs 2x4096  (32 KB)
  short* As = smem;
  short* Bs = smem + 8192;
  const int tid = threadIdx.x;
  const int wave = tid >> 6, lane = tid & 63;
  const int g = lane >> 4, li = lane & 15, li2 = li >> 1;

  // T1: bijective XCD-chunked swizzle (nwg % 8 == 0 for all launches)
  const int nx = gridDim.x;
  const int nwg = nx * gridDim.y;
  int bid = blockIdx.y * nx + blockIdx.x;
  const int cpx = nwg >> 3;
  bid = (bid & 7) * cpx + (bid >> 3);
  const int m0 = (bid / nx) << 7, n0 = (bid % nx) << 7;

  // staging source (per lane): LDS linear slot holds swizzled source
  const int hi = lane >> 3, lo = lane & 7;
  const int su = lo ^ hi;                  // unit-slot held by this lane
  const int srow = hi * 2 + (su >> 2);     // + chunk*16 rows
  const int scol = (su & 3) << 3;
  const short* gA = A + (size_t)(m0 + wave * 16 + srow) * KDIM + scol;
  const short* gB = Bt + (size_t)(n0 + wave * 16 + srow) * KDIM + scol;
  short* lA = As + wave * 512;             // + buf*4096 + p*2048
  short* lB = Bs + wave * 512;

  // fragment read addressing
  const int wm = wave >> 1, wn = wave & 1;
  const int slot = ((((li & 1) << 2) + g) ^ li2) << 3;   // shorts
  const int abase = (wm * 32 + li2) * 64 + slot;         // + mi*512
  const int bbase = (wn * 32 + li2) * 64 + slot;         // + ni*512

  f32x4 acc[4][4] = {};

#define STAGE(buf, kt)                                                        \
  do {                                                                        \
    gload_lds16(gA + (kt), lA + (buf) * 4096);                                \
    gload_lds16(gA + (size_t)64 * KDIM + (kt), lA + (buf) * 4096 + 2048);     \
    gload_lds16(gB + (kt), lB + (buf) * 4096);                                \
    gload_lds16(gB + (size_t)64 * KDIM + (kt), lB + (buf) * 4096 + 2048);     \
  } while (0)

#define COMPUTE(buf)                                                          \
  do {                                                                        \
    const short* pa = As + (buf) * 4096 + abase;                              \
    const short* pb = Bs + (buf) * 4096 + bbase;                              \
    bf16x8_t a[4], b[4];                                                      \
    _Pragma("unroll") for (int i = 0; i < 4; i++) {                           \
      a[i] = *(const bf16x8_t*)(pa + i * 512);                                \
      b[i] = *(const bf16x8_t*)(pb + i * 512);                                \
    }                                                                         \
    _Pragma("unroll") for (int mi = 0; mi < 4; mi++)                          \
        _Pragma("unroll") for (int ni = 0; ni < 4; ni++) acc[mi][ni] =        \
        __builtin_amdgcn_mfma_f32_16x16x32_bf16(a[mi], b[ni], acc[mi][ni],    \
                                                0, 0, 0);                     \
  } while (0)

  constexpr int NT = KDIM / 32;
  STAGE(0, 0);
#pragma unroll 2
  for (int t = 0; t < NT; ++t) {
    asm volatile("s_waitcnt lgkmcnt(0)" ::: "memory");
    __builtin_amdgcn_s_barrier();        // prev-buf reads retired everywhere
    if (t + 1 < NT) {
      STAGE((t + 1) & 1, (t + 1) * 32);
      asm volatile("s_waitcnt vmcnt(4)" ::: "memory");   // tile t landed
    } else {
      asm volatile("s_waitcnt vmcnt(0)" ::: "memory");
    }
    __builtin_amdgcn_s_barrier();        // buf t&1 staged for all waves
    COMPUTE(t & 1);
  }
#undef STAGE
#undef COMPUTE

  // epilogue: row = m0+wm*64+mi*16+g*4+r ; col = n0+wn*64+ni*16+li
  if constexpr (EPI == 0) {
    const int s = n0 / 384;
    const int nloc = n0 % 384;           // 0,128,256
    if (s < 2) {                         // q/k: direct 2B stores (32B runs)
      short* dst = (s == 0) ? ob0 : ob1;
      const float scale = (s == 0) ? 0.17677669529663687f : 1.f;
#pragma unroll
      for (int mi = 0; mi < 4; mi++) {
#pragma unroll
        for (int ni = 0; ni < 4; ni++) {
          const int colc = wn * 64 + ni * 16 + li;
          const float bc = bias[n0 + colc];
          const int head = (nloc + colc) >> 5, d = colc & 31;
#pragma unroll
          for (int r = 0; r < 4; r++) {
            const int row = m0 + wm * 64 + mi * 16 + g * 4 + r;
            const int widx = row >> 6, n = row & 63;
            dst[(((size_t)widx * 12 + head) * 64 + n) * 32 + d] =
                f2bf((acc[mi][ni][r] + bc) * scale);
          }
        }
      }
    } else {                             // v: LDS-staged transpose store
      __syncthreads();
      short* ct = smem;                  // 16384 shorts = [2][4][32 d][64 n]
#pragma unroll
      for (int mi = 0; mi < 4; mi++) {
#pragma unroll
        for (int ni = 0; ni < 4; ni++) {
          const int colc = wn * 64 + ni * 16 + li;
          const float bc = bias[n0 + colc];
          const int hh = colc >> 5, d = colc & 31;
#pragma unroll
          for (int r = 0; r < 4; r++) {
            const int rowloc = wm * 64 + mi * 16 + g * 4 + r;
            const int wl = rowloc >> 6, n = rowloc & 63;
            int idx16 = (wl * 4 + hh) * 256 + d * 8 + (n >> 3);
            idx16 ^= (idx16 >> 3) & 7;
            ct[idx16 * 8 + (n & 7)] = f2bf(acc[mi][ni][r] + bc);
          }
        }
      }
      __syncthreads();
      const int hb = nloc >> 5;
      const int wg0 = m0 >> 6;
#pragma unroll
      for (int k2 = 0; k2 < 8; k2++) {
        const int c = k2 * 256 + tid;    // 16B chunk id, 0..2047
        const int cs = c ^ ((c >> 3) & 7);
        i32x4 val = *(const i32x4*)(ct + cs * 8);
        const int run = c >> 8, sub2 = c & 255;
        short* gp = ob2 +
                    ((size_t)(wg0 + (run >> 2)) * 12 + hb + (run & 3)) * 2048 +
                    sub2 * 8;
        *(i32x4*)gp = val;
      }
    }
  } else if constexpr (EPI == 2) {       // FC1 + GELU, direct 2B stores
#pragma unroll
    for (int mi = 0; mi < 4; mi++) {
#pragma unroll
      for (int ni = 0; ni < 4; ni++) {
        const int col = n0 + wn * 64 + ni * 16 + li;
        const float bc = bias[col];
#pragma unroll
        for (int r = 0; r < 4; r++) {
          const int row = m0 + wm * 64 + mi * 16 + g * 4 + r;
          ob0[(size_t)row * 1536 + col] = f2bf(fgelu(acc[mi][ni][r] + bc));
        }
      }
    }
  } else {                               // EPI 1 / 3: f32 + residual
#pragma unroll
    for (int mi = 0; mi < 4; mi++) {
#pragma unroll
      for (int ni = 0; ni < 4; ni++) {
        const int col = n0 + wn * 64 + ni * 16 + li;
        const float bc = bias[col];
        const int rbase = m0 + wm * 64 + mi * 16 + g * 4;
        if constexpr (EPI == 1) {
#pragma unroll
          for (int r = 0; r < 4; r++) {
            const int row = rbase + r;
            const int widx = row >> 6, n = row & 63;
            const int wloc = widx & 255, bb = widx >> 8;
            const int z = ((wloc >> 6) << 2) + (n >> 4);
            const int h = (((wloc >> 3) & 7) << 2) + ((n >> 2) & 3);
            const int w = ((wloc & 7) << 2) + (n & 3);
            const int zs = (z + 2) & 15, hs = (h + 2) & 31, wsx = (w + 2) & 31;
            const size_t t = (size_t)bb * 16384 + zs * 1024 + hs * 32 + wsx;
            of32[t * 384 + col] = aux[t * 384 + col] + acc[mi][ni][r] + bc;
          }
        } else {
#pragma unroll
          for (int r = 0; r < 4; r++) {
            const int row = rbase + r;
            of32[(size_t)row * 384 + col] =
                aux[(size_t)row * 384 + col] + acc[mi][ni][r] + bc;
          }
        }
      }
    }
  }
}

// ---------------- windowed attention: 4 waves/block, 1 wave per (win,head) --
__global__ __launch_bounds__(256) void k_attn(
    const short* __restrict__ qb, const short* __restrict__ kb,
    const short* __restrict__ vb, const float* __restrict__ relb,
    short* __restrict__ owin) {
  __shared__ short pt[4][5120];
  const int wave = threadIdx.x >> 6;
  const int wh_ = blockIdx.x * 4 + wave;
  const int widx = wh_ / 12, head = wh_ - widx * 12;
  const int lane = threadIdx.x & 63;
  const int g = lane >> 4, li = lane & 15;
  const short* qp = qb + (size_t)wh_ * 2048;
  const short* kp = kb + (size_t)wh_ * 2048;
  const short* vp = vb + (size_t)wh_ * 2048;
  short* ptw = pt[wave];
  bf16x8_t kf[4], qf[4];
#pragma unroll
  for (int t = 0; t < 4; t++) {
    kf[t] = *(const bf16x8_t*)(kp + (t * 16 + li) * 32 + g * 8);
    qf[t] = *(const bf16x8_t*)(qp + (t * 16 + li) * 32 + g * 8);
  }
  f32x4 zero = {0.f, 0.f, 0.f, 0.f};
  f32x4 st[4][4];
#pragma unroll
  for (int ti = 0; ti < 4; ti++)
#pragma unroll
    for (int tj = 0; tj < 4; tj++)
      st[ti][tj] = __builtin_amdgcn_mfma_f32_16x16x32_bf16(kf[ti], qf[tj], zero, 0, 0, 0);
  const int wloc = widx & 255;
  const int wz = wloc >> 6, wh2 = (wloc >> 3) & 7, ww2 = wloc & 7;
#pragma unroll
  for (int tj = 0; tj < 4; tj++) {
    const int qn = tj * 16 + li;
    const int qz = qn >> 4, qh = (qn >> 2) & 3, qw = qn & 3;
    const int cq = ((wz < 3) ? 0 : ((qz < 2) ? 1 : 2)) * 9 +
                   ((wh2 < 7) ? 0 : ((qh < 2) ? 1 : 2)) * 3 +
                   ((ww2 < 7) ? 0 : ((qw < 2) ? 1 : 2));
    float mx = -1e30f;
#pragma unroll
    for (int ti = 0; ti < 4; ti++) {
#pragma unroll
      for (int r = 0; r < 4; r++) {
        const int kn = ti * 16 + g * 4 + r;
        const int kz = kn >> 4, kh = (kn >> 2) & 3, kw = kn & 3;
        const int ck = ((wz < 3) ? 0 : ((kz < 2) ? 1 : 2)) * 9 +
                       ((wh2 < 7) ? 0 : ((kh < 2) ? 1 : 2)) * 3 +
                       ((ww2 < 7) ? 0 : ((kw < 2) ? 1 : 2));
        const int idx = (qz - kz + 3) * 49 + (qh - kh + 3) * 7 + (qw - kw + 3);
        float v = st[ti][tj][r] + relb[idx * 12 + head] + ((ck == cq) ? 0.f : -100.f);
        st[ti][tj][r] = v;
        mx = fmaxf(mx, v);
      }
    }
    mx = fmaxf(mx, __shfl_xor(mx, 16));
    mx = fmaxf(mx, __shfl_xor(mx, 32));
    float sum = 0.f;
#pragma unroll
    for (int ti = 0; ti < 4; ti++)
#pragma unroll
      for (int r = 0; r < 4; r++) {
        float e = __expf(st[ti][tj][r] - mx);
        st[ti][tj][r] = e;
        sum += e;
      }
    sum += __shfl_xor(sum, 16);
    sum += __shfl_xor(sum, 32);
    const float rs = 1.f / sum;
#pragma unroll
    for (int ti = 0; ti < 4; ti++)
#pragma unroll
      for (int r = 0; r < 4; r++)
        ptw[qn * 80 + ti * 16 + g * 4 + r] = f2bf(st[ti][tj][r] * rs);
  }
  __syncthreads();
  f32x4 o[4][2] = {};
#pragma unroll
  for (int kb2 = 0; kb2 < 2; kb2++) {
    bf16x8_t pa[4], bv[2];
#pragma unroll
    for (int tq = 0; tq < 4; tq++)
      pa[tq] = *(const bf16x8_t*)(ptw + (tq * 16 + li) * 80 + kb2 * 32 + g * 8);
#pragma unroll
    for (int td = 0; td < 2; td++)
      bv[td] = *(const bf16x8_t*)(vp + (td * 16 + li) * 64 + kb2 * 32 + g * 8);
#pragma unroll
    for (int tq = 0; tq < 4; tq++)
#pragma unroll
      for (int td = 0; td < 2; td++)
        o[tq][td] = __builtin_amdgcn_mfma_f32_16x16x32_bf16(pa[tq], bv[td], o[tq][td], 0, 0, 0);
  }
#pragma unroll
  for (int tq = 0; tq < 4; tq++)
#pragma unroll
    for (int td = 0; td < 2; td++)
#pragma unroll
      for (int r = 0; r < 4; r++) {
        const int qn = tq * 16 + g * 4 + r;
        const int d = td * 16 + li;
        owin[((size_t)widx * 64 + qn) * 384 + head * 32 + d] = f2bf(o[tq][td][r]);
      }
}

// ---------------------------------------------------------------------------
extern "C" void kernel_launch(void* const* d_in, const int* in_sizes, int n_in,
                              void* d_out, int out_size, void* d_ws,
                              size_t ws_size, hipStream_t stream) {
  (void)in_sizes; (void)n_in; (void)out_size; (void)ws_size;
  const float* x      = (const float*)d_in[0];
  const float* n1g    = (const float*)d_in[1];
  const float* n1b    = (const float*)d_in[2];
  const float* qkv_w  = (const float*)d_in[3];
  const float* qkv_b  = (const float*)d_in[4];
  const float* proj_w = (const float*)d_in[5];
  const float* proj_b = (const float*)d_in[6];
  const float* relb   = (const float*)d_in[7];
  const float* n2g    = (const float*)d_in[8];
  const float* n2b    = (const float*)d_in[9];
  const float* fc1_w  = (const float*)d_in[10];
  const float* fc1_b  = (const float*)d_in[11];
  const float* fc2_w  = (const float*)d_in[12];
  const float* fc2_b  = (const float*)d_in[13];
  float* out = (float*)d_out;
  char* ws = (char*)d_ws;

  short* qbuf = (short*)(ws + OFF_Q);
  short* kbuf = (short*)(ws + OFF_K);
  short* vbuf = (short*)(ws + OFF_V);
  short* hid  = (short*)(ws + OFF_HID);
  short* win  = (short*)(ws + OFF_WIN);
  short* owin = (short*)(ws + OFF_WIN);
  short* h2   = (short*)(ws + OFF_WIN);
  float* x2   = out;
  short* wq   = (short*)(ws + OFF_WQ);
  short* wp   = (short*)(ws + OFF_WP);
  short* w1   = (short*)(ws + OFF_W1);
  short* w2   = (short*)(ws + OFF_W2);

  k_w2bf_t<384, 1152><<<(384 * 1152 + 255) / 256, 256, 0, stream>>>(qkv_w, wq);
  k_w2bf_t<384, 384><<<(384 * 384 + 255) / 256, 256, 0, stream>>>(proj_w, wp);
  k_w2bf_t<384, 1536><<<(384 * 1536 + 255) / 256, 256, 0, stream>>>(fc1_w, w1);
  k_w2bf_t<1536, 384><<<(1536 * 384 + 255) / 256, 256, 0, stream>>>(fc2_w, w2);

  k_ln1_window<<<16384, 256, 0, stream>>>(x, n1g, n1b, win);
  k_gemm<0, 384><<<dim3(9, 512), 256, 0, stream>>>(win, wq, qkv_b, qbuf, kbuf,
                                                   vbuf, nullptr, nullptr);
  k_attn<<<3072, 256, 0, stream>>>(qbuf, kbuf, vbuf, relb, owin);
  k_gemm<1, 384><<<dim3(3, 512), 256, 0, stream>>>(owin, wp, proj_b, nullptr,
                                                   nullptr, nullptr, x, x2);
  k_ln2<<<16384, 256, 0, stream>>>(x2, n2g, n2b, h2);
  k_gemm<2, 384><<<dim3(12, 512), 256, 0, stream>>>(h2, w1, fc1_b, hid, nullptr,
                                                    nullptr, nullptr, nullptr);
  k_gemm<3, 1536><<<dim3(3, 512), 256, 0, stream>>>(hid, w2, fc2_b, nullptr,
                                                    nullptr, nullptr, x2, out);
}